// Round 4
// baseline (751.625 us; speedup 1.0000x reference)
//
#include <hip/hip_runtime.h>
#include <stdint.h>

#define BB 256      // batch
#define TT 200      // timesteps
#define INN 1568    // inputs
#define OO 100      // outputs
#define PAIRS 784   // INN/2
#define NHALF 12800 // (BB*OO)/2
#define NBLK 240    // co-resident grid (1 block/CU guaranteed)
#define ROWSTRIDE (4 * INN)

typedef unsigned long long u64;
typedef __attribute__((ext_vector_type(4))) int v4i;

// ---------------- threefry2x32 (JAX-compatible) ----------------
__device__ __forceinline__ void tf_round(uint32_t& x0, uint32_t& x1, int r) {
    x0 += x1;
    x1 = (x1 << r) | (x1 >> (32 - r));
    x1 ^= x0;
}

__device__ __forceinline__ void threefry(uint32_t k0, uint32_t k1,
                                         uint32_t x0, uint32_t x1,
                                         uint32_t& o0, uint32_t& o1) {
    uint32_t k2 = k0 ^ k1 ^ 0x1BD11BDAu;
    x0 += k0; x1 += k1;
    tf_round(x0,x1,13); tf_round(x0,x1,15); tf_round(x0,x1,26); tf_round(x0,x1,6);
    x0 += k1; x1 += k2 + 1u;
    tf_round(x0,x1,17); tf_round(x0,x1,29); tf_round(x0,x1,16); tf_round(x0,x1,24);
    x0 += k2; x1 += k0 + 2u;
    tf_round(x0,x1,13); tf_round(x0,x1,15); tf_round(x0,x1,26); tf_round(x0,x1,6);
    x0 += k0; x1 += k1 + 3u;
    tf_round(x0,x1,17); tf_round(x0,x1,29); tf_round(x0,x1,16); tf_round(x0,x1,24);
    x0 += k1; x1 += k2 + 4u;
    tf_round(x0,x1,13); tf_round(x0,x1,15); tf_round(x0,x1,26); tf_round(x0,x1,6);
    o0 = x0 + k2; o1 = x1 + k0 + 5u;
}

// ---------------- LDS (phases time-separated by gridsync) ----------------
struct FwSM { uint32_t wl32[TT * 65]; int fwl[BB]; };            // 53 KB (phase B)
struct D1SM { u64 winS[2][OO][4]; u64 postS[2][OO][4]; };        // 12.8 KB (phase D1)
union PhaseSM { FwSM w; D1SM d; };

__device__ __forceinline__ void gridsync(uint32_t* c) {
    __syncthreads();
    if (threadIdx.x == 0) {
        __threadfence();   // release this block's stores (agent scope)
        __hip_atomic_fetch_add(c, 1u, __ATOMIC_ACQ_REL, __HIP_MEMORY_SCOPE_AGENT);
        while (__hip_atomic_load(c, __ATOMIC_ACQUIRE, __HIP_MEMORY_SCOPE_AGENT)
               < (uint32_t)NBLK)
            __builtin_amdgcn_s_sleep(8);
        __threadfence();
    }
    __syncthreads();
}

#define POPC4(A0,A1,A2,A3,B0,B1,B2,B3) \
    (__popcll((A0)&(B0)) + __popcll((A1)&(B1)) + \
     __popcll((A2)&(B2)) + __popcll((A3)&(B3)))

__global__ __launch_bounds__(512, 1) void k_mono(
        const int* __restrict__ x,
        const float* __restrict__ L0,
        const float* __restrict__ p0arr,
        uint32_t* __restrict__ syncc,
        uint8_t* __restrict__ widx,
        uint32_t* __restrict__ cntg,
        u64* __restrict__ winbits,
        u64* __restrict__ postbits,
        u64* __restrict__ bitB,
        uint32_t* __restrict__ packed,
        float* __restrict__ outL,
        float* __restrict__ outp) {
    __shared__ PhaseSM sm;
    __shared__ uint32_t smclaim;
    const int tid = threadIdx.x;
    const int bid = blockIdx.x;

    // ====== phase A: winners, spread over ALL 240 blocks (<=1 per thread) ==
    {
        int idx = bid * 214 + tid;       // 240*214 = 51360 >= 51200
        if (tid < 214 && idx < TT * BB) {
            int t = idx >> 8, b = idx & 255;
            uint32_t fk0, fk1;
            threefry(0u, 42u, 0u, (uint32_t)t, fk0, fk1);  // fold_in(key(42), t)
            uint32_t bestkey = 0u;
            int bo = 0;
            int nbase = b * OO;
            for (int o = 0; o < OO; ++o) {
                uint32_t n = (uint32_t)(nbase + o);
                uint32_t lo = (n < NHALF) ? n : n - NHALF;
                uint32_t v0, v1;
                threefry(fk0, fk1, lo, lo + NHALF, v0, v1);
                uint32_t bits = (n < NHALF) ? v0 : v1;
                uint32_t key = bits >> 9;   // monotone proxy for gumbel
                if (key > bestkey) { bestkey = key; bo = o; }
            }
            widx[idx] = (uint8_t)bo;
        }
    }
    gridsync(&syncc[0]);

    // ====== phase B (blocks 0..99): fwpost; then everyone joins C's queue ==
    if (bid < 100) {
        const uint32_t* wsrc = (const uint32_t*)widx;
        for (int g = tid; g < TT * 64; g += 512)
            sm.w.wl32[(g >> 6) * 65 + (g & 63)] = wsrc[g];
        __syncthreads();
        int o = bid;
        if (tid < 64) {
            int f0 = 255, f1 = 255, f2 = 255, f3 = 255;
            for (int t = 0; t < TT; ++t) {
                uint32_t w4 = sm.w.wl32[t * 65 + tid];
                if (((w4      ) & 255u) == (uint32_t)o && f0 == 255) f0 = t;
                if (((w4 >>  8) & 255u) == (uint32_t)o && f1 == 255) f1 = t;
                if (((w4 >> 16) & 255u) == (uint32_t)o && f2 == 255) f2 = t;
                if (((w4 >> 24) & 255u) == (uint32_t)o && f3 == 255) f3 = t;
            }
            sm.w.fwl[4 * tid + 0] = f0; sm.w.fwl[4 * tid + 1] = f1;
            sm.w.fwl[4 * tid + 2] = f2; sm.w.fwl[4 * tid + 3] = f3;
        }
        __syncthreads();
        if (tid < TT) {
            int t = tid;
            u64 wbA[4], pbA[4];
            uint32_t c = 0;
            #pragma unroll
            for (int k = 0; k < 4; ++k) {
                u64 wacc = 0, pacc = 0;
                for (int q2 = 0; q2 < 16; ++q2) {
                    uint32_t w4 = sm.w.wl32[t * 65 + k * 16 + q2];
                    #pragma unroll
                    for (int j = 0; j < 4; ++j) {
                        int bl = q2 * 4 + j;
                        bool win = (((w4 >> (8 * j)) & 255u) == (uint32_t)o);
                        c += win ? 1u : 0u;
                        bool post = (sm.w.fwl[k * 64 + q2 * 4 + j] < t) && !win;
                        u64 bit = 1ull << bl;
                        if (win)  wacc |= bit;
                        if (post) pacc |= bit;
                    }
                }
                wbA[k] = wacc; pbA[k] = pacc;
            }
            size_t base = (size_t)(t * OO + o) * 4;
            #pragma unroll
            for (int k = 0; k < 4; ++k) {
                winbits[base + k] = wbA[k];
                postbits[base + k] = pbA[k];
            }
            cntg[t * OO + o] = c;
        }
        __syncthreads();
    }

    // ====== phase C: bit-pack via atomic work queue (all blocks) ===========
    {
        const v4i* xp = (const v4i*)x;
        for (;;) {
            __syncthreads();
            if (tid == 0)
                smclaim = __hip_atomic_fetch_add(&syncc[2], 1u, __ATOMIC_RELAXED,
                                                 __HIP_MEMORY_SCOPE_AGENT);
            __syncthreads();
            uint32_t u = smclaim;
            if (u >= 200u) break;
            int wb = u & 3, tc = u >> 2;
            u64 acc[4][4];
            #pragma unroll
            for (int q = 0; q < 4; ++q)
                #pragma unroll
                for (int c = 0; c < 4; ++c) acc[q][c] = 0;
            bool x4 = (tid < 32);          // 1568 = 3*512 + 32
            for (int bl = 0; bl < 64; ++bl) {
                size_t base = ((size_t)((wb * 64 + bl) * TT + tc * 4)) * 392;
                u64 bit = 1ull << bl;
                #pragma unroll
                for (int q = 0; q < 3; ++q) {
                    v4i v = __builtin_nontemporal_load(&xp[base + tid + q * 512]);
                    if (v.x) acc[q][0] |= bit;
                    if (v.y) acc[q][1] |= bit;
                    if (v.z) acc[q][2] |= bit;
                    if (v.w) acc[q][3] |= bit;
                }
                if (x4) {
                    v4i v = __builtin_nontemporal_load(&xp[base + tid + 1536]);
                    if (v.x) acc[3][0] |= bit;
                    if (v.y) acc[3][1] |= bit;
                    if (v.z) acc[3][2] |= bit;
                    if (v.w) acc[3][3] |= bit;
                }
            }
            #pragma unroll
            for (int q = 0; q < 4; ++q) {
                if (q == 3 && !x4) continue;
                int p = tid + q * 512;
                int tp = (p >= 1176) ? 3 : (p >= 784) ? 2 : (p >= 392) ? 1 : 0;
                int iq = p - tp * 392;
                u64* dst = bitB + ((size_t)((tc * 4 + tp) * 4 + wb)) * INN + iq * 4;
                dst[0] = acc[q][0]; dst[1] = acc[q][1];
                dst[2] = acc[q][2]; dst[3] = acc[q][3];
            }
        }
    }
    gridsync(&syncc[1]);

    // ====== phase D1: packed lt/pp counts, queue over 200 (2t x 392p) units
    {
        for (;;) {
            __syncthreads();
            if (tid == 0)
                smclaim = __hip_atomic_fetch_add(&syncc[3], 1u, __ATOMIC_RELAXED,
                                                 __HIP_MEMORY_SCOPE_AGENT);
            __syncthreads();
            uint32_t u = smclaim;
            if (u >= 200u) break;
            int tc = (int)(u >> 1), ph = (int)(u & 1);
            int t0 = tc * 2;                        // covers t0, t0+1 (<=199)
            // stage win/post for t0, t0+1
            for (int g = tid; g < 800; g += 512) {
                int tt2 = g / 400;
                int rem = g - tt2 * 400;
                int oo = rem >> 2, k = rem & 3;
                size_t gi = ((size_t)(t0 + tt2) * OO + oo) * 4 + k;
                sm.d.winS[tt2][oo][k]  = winbits[gi];
                sm.d.postS[tt2][oo][k] = postbits[gi];
            }
            int p = ph * 392 + tid;
            bool act = (tid < 392);
            u64 pot0[8], pot1[8], ltp0[8], ltp1[8];
            if (act) {
                // window: c = OR(rows t0-8..t0); pot(t0)=c|r[t0-9];
                // pot(t0+1)=c|r[t0+1]; ltp(t)=pot(t)|r[t-10]; ltp(t+1)=pot(t+1)|r[t-9]
                u64 cc[8] = {0,0,0,0,0,0,0,0};
                u64 m10[8], m9[8], pl1[8], tmp[8];
                auto rowload = [&](int rr, u64* dst) {
                    const u64* base = bitB + (size_t)(rr * 4) * INN;
                    #pragma unroll
                    for (int wb = 0; wb < 4; ++wb) {
                        dst[wb]     = base[(size_t)wb * INN + p];
                        dst[4 + wb] = base[(size_t)wb * INN + p + PAIRS];
                    }
                };
                for (int r = -8; r <= 0; ++r) {
                    int rr = t0 + r; if (rr < 0) rr = 0;   // OR-idempotent clamp
                    rowload(rr, tmp);
                    #pragma unroll
                    for (int k = 0; k < 8; ++k) cc[k] |= tmp[k];
                }
                int rm10 = t0 - 10; if (rm10 < 0) rm10 = 0;
                int rm9  = t0 - 9;  if (rm9  < 0) rm9  = 0;
                rowload(rm10, m10);
                rowload(rm9,  m9);
                rowload(t0 + 1, pl1);
                #pragma unroll
                for (int k = 0; k < 8; ++k) {
                    pot0[k] = cc[k] | m9[k];
                    pot1[k] = cc[k] | pl1[k];
                    ltp0[k] = pot0[k] | m10[k];
                    ltp1[k] = pot1[k] | m9[k];
                }
            }
            __syncthreads();
            if (act) {
                for (int oo = 0; oo < OO; ++oo) {
                    u64 W0 = sm.d.winS[0][oo][0], W1 = sm.d.winS[0][oo][1];
                    u64 W2 = sm.d.winS[0][oo][2], W3 = sm.d.winS[0][oo][3];
                    u64 S0 = sm.d.postS[0][oo][0], S1 = sm.d.postS[0][oo][1];
                    u64 S2 = sm.d.postS[0][oo][2], S3 = sm.d.postS[0][oo][3];
                    uint32_t lt0 = POPC4(ltp0[0],ltp0[1],ltp0[2],ltp0[3], W0,W1,W2,W3);
                    uint32_t lt1 = POPC4(ltp0[4],ltp0[5],ltp0[6],ltp0[7], W0,W1,W2,W3);
                    uint32_t pp0 = POPC4(pot0[0],pot0[1],pot0[2],pot0[3], S0,S1,S2,S3);
                    uint32_t pp1 = POPC4(pot0[4],pot0[5],pot0[6],pot0[7], S0,S1,S2,S3);
                    lt0 = (lt0 > 255u) ? 255u : lt0;  pp0 = (pp0 > 255u) ? 255u : pp0;
                    lt1 = (lt1 > 255u) ? 255u : lt1;  pp1 = (pp1 > 255u) ? 255u : pp1;
                    packed[((size_t)t0 * OO + oo) * PAIRS + p] =
                        lt0 | (pp0 << 8) | (lt1 << 16) | (pp1 << 24);
                    W0 = sm.d.winS[1][oo][0]; W1 = sm.d.winS[1][oo][1];
                    W2 = sm.d.winS[1][oo][2]; W3 = sm.d.winS[1][oo][3];
                    S0 = sm.d.postS[1][oo][0]; S1 = sm.d.postS[1][oo][1];
                    S2 = sm.d.postS[1][oo][2]; S3 = sm.d.postS[1][oo][3];
                    lt0 = POPC4(ltp1[0],ltp1[1],ltp1[2],ltp1[3], W0,W1,W2,W3);
                    lt1 = POPC4(ltp1[4],ltp1[5],ltp1[6],ltp1[7], W0,W1,W2,W3);
                    pp0 = POPC4(pot1[0],pot1[1],pot1[2],pot1[3], S0,S1,S2,S3);
                    pp1 = POPC4(pot1[4],pot1[5],pot1[6],pot1[7], S0,S1,S2,S3);
                    lt0 = (lt0 > 255u) ? 255u : lt0;  pp0 = (pp0 > 255u) ? 255u : pp0;
                    lt1 = (lt1 > 255u) ? 255u : lt1;  pp1 = (pp1 > 255u) ? 255u : pp1;
                    packed[((size_t)(t0 + 1) * OO + oo) * PAIRS + p] =
                        lt0 | (pp0 << 8) | (lt1 << 16) | (pp1 << 24);
                }
            }
        }
    }
    gridsync(&syncc[4]);

    // ====== phase D2: chains (proven K4 structure), 1301 wave-units =======
    {
        const int wv = tid >> 6, lane = tid & 63;
        int u = bid * 8 + wv;
        if (u > 1300) return;
        if (u == 1300) {                            // ---- prior chain ----
            int l = lane;
            bool has2 = (l + 64) < OO;
            float pa = p0arr[l];
            float pb = has2 ? p0arr[l + 64] : -1e30f;
            auto norm = [&]() {
                pa = fminf(fmaxf(pa, -5.0f), 0.0f);
                if (has2) pb = fminf(fmaxf(pb, -5.0f), 0.0f);
                float mx = has2 ? fmaxf(pa, pb) : pa;
                #pragma unroll
                for (int s = 32; s > 0; s >>= 1) mx = fmaxf(mx, __shfl_xor(mx, s, 64));
                float smv = expf(pa - mx) + (has2 ? expf(pb - mx) : 0.0f);
                #pragma unroll
                for (int s = 32; s > 0; s >>= 1) smv += __shfl_xor(smv, s, 64);
                float lse = logf(smv) + mx;
                pa -= lse;
                if (has2) pb -= lse;
            };
            norm();
            for (int t = 0; t < TT; ++t) {
                float eta = 0.001f / (float)(t + 1);
                float wma = (float)cntg[t * OO + l] * (1.0f / 256.0f);
                pa += eta * ((-5.0f * pa - 1.0f) * wma - (1.0f - wma));
                if (has2) {
                    float wmb = (float)cntg[t * OO + l + 64] * (1.0f / 256.0f);
                    pb += eta * ((-5.0f * pb - 1.0f) * wmb - (1.0f - wmb));
                }
                norm();
            }
            outp[l] = pa;
            if (has2) outp[l + 64] = pb;
            return;
        }
        int o = u / 13, px = u - (u / 13) * 13;
        int p = px * 64 + lane;
        if (p >= PAIRS) return;
        int i0 = p, i1 = p + PAIRS;
        float a  = L0[(size_t)i0 * OO + o];
        float b2 = L0[(size_t)i1 * OO + o];
        a  = fminf(fmaxf(a,  -5.0f), 0.0f);
        b2 = fminf(fmaxf(b2, -5.0f), 0.0f);
        {
            float m = fmaxf(a, b2), mn = fminf(a, b2);
            float lse = __logf(1.0f + __expf(mn - m)) + m;
            a -= lse; b2 -= lse;
        }
        const uint32_t* src = packed + (size_t)o * PAIRS + p;
        const size_t tstride = (size_t)OO * PAIRS;
        uint32_t c[16];
        #pragma unroll
        for (int k = 0; k < 16; ++k)
            c[k] = src[(size_t)k * tstride];
        #pragma unroll 16
        for (int tl = 0; tl < TT; ++tl) {
            uint32_t cur = c[tl & 15];
            int nx = tl + 16; if (nx >= TT) nx = TT - 1;
            c[tl & 15] = src[(size_t)nx * tstride];
            float cwin = (float)cntg[tl * OO + o];
            float lt0 = (float)(cur & 255u),         pp0 = (float)((cur >> 8) & 255u);
            float lt1 = (float)((cur >> 16) & 255u), pp1 = (float)(cur >> 24);
            float eta = 0.001f / (float)(tl + 1);
            float dw0 = (5.0f * __expf(-a)  - 1.0f) * (lt0 * (1.0f/256.0f))
                      + (cwin - lt0 - pp0) * (1.0f/256.0f);
            float dw1 = (5.0f * __expf(-b2) - 1.0f) * (lt1 * (1.0f/256.0f))
                      + (cwin - lt1 - pp1) * (1.0f/256.0f);
            a  += eta * dw0;
            b2 += eta * dw1;
            a  = fminf(fmaxf(a,  -5.0f), 0.0f);
            b2 = fminf(fmaxf(b2, -5.0f), 0.0f);
            float m = fmaxf(a, b2), mn = fminf(a, b2);
            float lse = __logf(1.0f + __expf(mn - m)) + m;
            a -= lse; b2 -= lse;
        }
        outL[(size_t)i0 * OO + o] = a;
        outL[(size_t)i1 * OO + o] = b2;
    }
}

extern "C" void kernel_launch(void* const* d_in, const int* in_sizes, int n_in,
                              void* d_out, int out_size, void* d_ws, size_t ws_size,
                              hipStream_t stream) {
    const int*   x  = (const int*)d_in[0];
    const float* L0 = (const float*)d_in[1];
    const float* p0 = (const float*)d_in[2];
    float* out = (float*)d_out;

    char* ws = (char*)d_ws;
    size_t off = 0;
    auto alloc = [&](size_t bytes) -> void* {
        off = (off + 255) & ~(size_t)255;
        void* p = ws + off;
        off += bytes;
        return p;
    };
    uint32_t* syncc    = (uint32_t*)alloc(256);      // [0],[1],[4] sync; [2],[3] queues
    uint8_t*  widx     = (uint8_t*) alloc((size_t)TT * BB);
    uint32_t* cntg     = (uint32_t*)alloc((size_t)TT * OO * 4);
    u64*      winbits  = (u64*)     alloc((size_t)TT * OO * 4 * 8);
    u64*      postbits = (u64*)     alloc((size_t)TT * OO * 4 * 8);
    u64*      bitB     = (u64*)     alloc((size_t)TT * 4 * INN * 8);
    uint32_t* packed   = (uint32_t*)alloc((size_t)TT * OO * PAIRS * 4);  // 62.7 MB
    (void)ws_size;  // ws ~1.28 GB (fill poison size) — fits with big margin

    hipMemsetAsync(syncc, 0, 256, stream);   // zero sync/queue counters
    hipLaunchKernelGGL(k_mono, dim3(NBLK), dim3(512), 0, stream,
                       x, L0, p0, syncc, widx, cntg, winbits, postbits, bitB,
                       packed, out, out + (size_t)INN * OO);
}

// Round 5
// 689.136 us; speedup vs baseline: 1.0907x; 1.0907x over previous
//
#include <hip/hip_runtime.h>
#include <stdint.h>

#define BB 256      // batch
#define TT 200      // timesteps
#define INN 1568    // inputs
#define OO 100      // outputs
#define PAIRS 784   // INN/2
#define NHALF 12800 // (BB*OO)/2
#define NBLK 240    // co-resident grid (152KB LDS => 1 block/CU)
#define UNITS 686   // 98 pair-groups x 7 o-groups (chain wave-units)
#define ROWSTRIDE (4 * INN)

typedef unsigned long long u64;
typedef __attribute__((ext_vector_type(4))) int v4i;

// async global->LDS (16 B/lane); LDS dest = wave-uniform base + lane*16
typedef const __attribute__((address_space(1))) uint32_t* gas_p;
typedef __attribute__((address_space(3))) uint32_t* las_p;
#define GLD16(g, l) __builtin_amdgcn_global_load_lds((gas_p)(g), (las_p)(l), 16, 0, 0)

// ---------------- threefry2x32 (JAX-compatible) ----------------
__device__ __forceinline__ void tf_round(uint32_t& x0, uint32_t& x1, int r) {
    x0 += x1;
    x1 = (x1 << r) | (x1 >> (32 - r));
    x1 ^= x0;
}

__device__ __forceinline__ void threefry(uint32_t k0, uint32_t k1,
                                         uint32_t x0, uint32_t x1,
                                         uint32_t& o0, uint32_t& o1) {
    uint32_t k2 = k0 ^ k1 ^ 0x1BD11BDAu;
    x0 += k0; x1 += k1;
    tf_round(x0,x1,13); tf_round(x0,x1,15); tf_round(x0,x1,26); tf_round(x0,x1,6);
    x0 += k1; x1 += k2 + 1u;
    tf_round(x0,x1,17); tf_round(x0,x1,29); tf_round(x0,x1,16); tf_round(x0,x1,24);
    x0 += k2; x1 += k0 + 2u;
    tf_round(x0,x1,13); tf_round(x0,x1,15); tf_round(x0,x1,26); tf_round(x0,x1,6);
    x0 += k0; x1 += k1 + 3u;
    tf_round(x0,x1,17); tf_round(x0,x1,29); tf_round(x0,x1,16); tf_round(x0,x1,24);
    x0 += k1; x1 += k2 + 4u;
    tf_round(x0,x1,13); tf_round(x0,x1,15); tf_round(x0,x1,26); tf_round(x0,x1,6);
    o0 = x0 + k2; o1 = x1 + k0 + 5u;
}

// ---------------- shared memory union (phases are time-separated) ----------
struct FusedSM {
    u64 rows[8][16][64];        // [wave][row&15][k*8+pl]        64 KB
    u64 wp[8][8][128];          // [wave][t&7][win 64 | post 64]  64 KB
    u64 potC[8][2][8][10];      // [wave][step][pl][k pad->80B]   10 KB
    u64 ltpC[8][2][8][10];      //                                10 KB
    uint32_t cntR[8][8][16];    // [wave][t&7][o-local]            4 KB
};
struct FwSM { uint32_t wl32[TT * 65]; int fwl[BB]; };
union SMem { FusedSM f; FwSM w; };

__device__ __forceinline__ void gridsync(uint32_t* c) {
    __syncthreads();
    if (threadIdx.x == 0) {
        __threadfence();   // release this block's stores (agent scope)
        __hip_atomic_fetch_add(c, 1u, __ATOMIC_ACQ_REL, __HIP_MEMORY_SCOPE_AGENT);
        while (__hip_atomic_load(c, __ATOMIC_ACQUIRE, __HIP_MEMORY_SCOPE_AGENT)
               < (uint32_t)NBLK)
            __builtin_amdgcn_s_sleep(8);
        __threadfence();
    }
    __syncthreads();
}

__global__ __launch_bounds__(512, 1) void k_mono(
        const int* __restrict__ x,
        const float* __restrict__ L0,
        const float* __restrict__ p0arr,
        uint32_t* __restrict__ syncc,
        uint8_t* __restrict__ widx,
        uint32_t* __restrict__ cntg,
        u64* __restrict__ winbits,
        u64* __restrict__ postbits,
        u64* __restrict__ bitB,
        float* __restrict__ outL,
        float* __restrict__ outp) {
    __shared__ SMem sm;
    __shared__ uint32_t smclaim;
    const int tid = threadIdx.x;
    const int bid = blockIdx.x;

    // ====== phase A: winners, spread over ALL 240 blocks (<=1 per thread) ==
    {
        int idx = bid * 214 + tid;       // 240*214 = 51360 >= 51200
        if (tid < 214 && idx < TT * BB) {
            int t = idx >> 8, b = idx & 255;
            uint32_t fk0, fk1;
            threefry(0u, 42u, 0u, (uint32_t)t, fk0, fk1);  // fold_in(key(42), t)
            uint32_t bestkey = 0u;
            int bo = 0;
            int nbase = b * OO;
            for (int o = 0; o < OO; ++o) {
                uint32_t n = (uint32_t)(nbase + o);
                uint32_t lo = (n < NHALF) ? n : n - NHALF;
                uint32_t v0, v1;
                threefry(fk0, fk1, lo, lo + NHALF, v0, v1);
                uint32_t bits = (n < NHALF) ? v0 : v1;
                uint32_t key = bits >> 9;   // monotone proxy for gumbel
                if (key > bestkey) { bestkey = key; bo = o; }
            }
            widx[idx] = (uint8_t)bo;
        }
    }
    gridsync(&syncc[0]);

    // ====== phase B (blocks 0..99): fwpost; then everyone joins C's queue ==
    if (bid < 100) {
        const uint32_t* wsrc = (const uint32_t*)widx;
        for (int g = tid; g < TT * 64; g += 512)
            sm.w.wl32[(g >> 6) * 65 + (g & 63)] = wsrc[g];
        __syncthreads();
        int o = bid;
        if (tid < 64) {
            int f0 = 255, f1 = 255, f2 = 255, f3 = 255;
            for (int t = 0; t < TT; ++t) {
                uint32_t w4 = sm.w.wl32[t * 65 + tid];
                if (((w4      ) & 255u) == (uint32_t)o && f0 == 255) f0 = t;
                if (((w4 >>  8) & 255u) == (uint32_t)o && f1 == 255) f1 = t;
                if (((w4 >> 16) & 255u) == (uint32_t)o && f2 == 255) f2 = t;
                if (((w4 >> 24) & 255u) == (uint32_t)o && f3 == 255) f3 = t;
            }
            sm.w.fwl[4 * tid + 0] = f0; sm.w.fwl[4 * tid + 1] = f1;
            sm.w.fwl[4 * tid + 2] = f2; sm.w.fwl[4 * tid + 3] = f3;
        }
        __syncthreads();
        if (tid < TT) {
            int t = tid;
            u64 wbA[4], pbA[4];
            uint32_t c = 0;
            #pragma unroll
            for (int k = 0; k < 4; ++k) {
                u64 wacc = 0, pacc = 0;
                for (int q2 = 0; q2 < 16; ++q2) {
                    uint32_t w4 = sm.w.wl32[t * 65 + k * 16 + q2];
                    #pragma unroll
                    for (int j = 0; j < 4; ++j) {
                        int bl = q2 * 4 + j;
                        bool win = (((w4 >> (8 * j)) & 255u) == (uint32_t)o);
                        c += win ? 1u : 0u;
                        bool post = (sm.w.fwl[k * 64 + q2 * 4 + j] < t) && !win;
                        u64 bit = 1ull << bl;
                        if (win)  wacc |= bit;
                        if (post) pacc |= bit;
                    }
                }
                wbA[k] = wacc; pbA[k] = pacc;
            }
            size_t base = (size_t)(t * OO + o) * 4;
            #pragma unroll
            for (int k = 0; k < 4; ++k) {
                winbits[base + k] = wbA[k];
                postbits[base + k] = pbA[k];
            }
            cntg[t * OO + o] = c;
        }
        __syncthreads();
    }

    // ====== phase C: bit-pack, atomic queue, 4x-batched loads ==============
    // In-flight depth is the lever: 12-16 independent 16B NT loads issued
    // before any consumption => ~12KB/wave in flight; 1920 waves => ~25MB
    // grid-wide vs ~6MB needed to saturate 6.3TB/s (R4 ran at 1TB/s with
    // VGPR=60 => ~1 iter lookahead).
    {
        const v4i* xp = (const v4i*)x;
        for (;;) {
            __syncthreads();
            if (tid == 0)
                smclaim = __hip_atomic_fetch_add(&syncc[2], 1u, __ATOMIC_RELAXED,
                                                 __HIP_MEMORY_SCOPE_AGENT);
            __syncthreads();
            uint32_t u = smclaim;
            if (u >= 200u) break;
            int wb = u & 3, tc = u >> 2;
            u64 acc[4][4];
            #pragma unroll
            for (int q = 0; q < 4; ++q)
                #pragma unroll
                for (int c = 0; c < 4; ++c) acc[q][c] = 0;
            bool x4 = (tid < 32);          // 1568 = 3*512 + 32
            for (int blb = 0; blb < 64; blb += 4) {
                v4i v[4][3];
                v4i vt[4];
                // -- issue 12 (+4 tail) independent loads --
                #pragma unroll
                for (int s4 = 0; s4 < 4; ++s4) {
                    size_t base = ((size_t)((wb * 64 + blb + s4) * TT + tc * 4)) * 392;
                    #pragma unroll
                    for (int q = 0; q < 3; ++q)
                        v[s4][q] = __builtin_nontemporal_load(&xp[base + tid + q * 512]);
                    if (x4)
                        vt[s4] = __builtin_nontemporal_load(&xp[base + tid + 1536]);
                }
                // -- consume --
                #pragma unroll
                for (int s4 = 0; s4 < 4; ++s4) {
                    u64 bit = 1ull << (blb + s4);
                    #pragma unroll
                    for (int q = 0; q < 3; ++q) {
                        if (v[s4][q].x) acc[q][0] |= bit;
                        if (v[s4][q].y) acc[q][1] |= bit;
                        if (v[s4][q].z) acc[q][2] |= bit;
                        if (v[s4][q].w) acc[q][3] |= bit;
                    }
                    if (x4) {
                        if (vt[s4].x) acc[3][0] |= bit;
                        if (vt[s4].y) acc[3][1] |= bit;
                        if (vt[s4].z) acc[3][2] |= bit;
                        if (vt[s4].w) acc[3][3] |= bit;
                    }
                }
            }
            #pragma unroll
            for (int q = 0; q < 4; ++q) {
                if (q == 3 && !x4) continue;
                int p = tid + q * 512;
                int tp = (p >= 1176) ? 3 : (p >= 784) ? 2 : (p >= 392) ? 1 : 0;
                int iq = p - tp * 392;
                u64* dst = bitB + ((size_t)((tc * 4 + tp) * 4 + wb)) * INN + iq * 4;
                dst[0] = acc[q][0]; dst[1] = acc[q][1];
                dst[2] = acc[q][2]; dst[3] = acc[q][3];
            }
        }
    }
    gridsync(&syncc[1]);

    // ====== phase D: wave-synchronous fused chains (R3 form, measured fast)
    {
        const int wv = tid >> 6, lane = tid & 63;
        int u = bid + NBLK * wv;
        if (u > UNITS) return;                      // idle waves
        if (u == UNITS) {                           // ---- prior chain ----
            int l = lane;
            bool has2 = (l + 64) < OO;
            float pa = p0arr[l];
            float pb = has2 ? p0arr[l + 64] : -1e30f;
            auto norm = [&]() {
                pa = fminf(fmaxf(pa, -5.0f), 0.0f);
                if (has2) pb = fminf(fmaxf(pb, -5.0f), 0.0f);
                float mx = has2 ? fmaxf(pa, pb) : pa;
                #pragma unroll
                for (int s = 32; s > 0; s >>= 1) mx = fmaxf(mx, __shfl_xor(mx, s, 64));
                float smv = expf(pa - mx) + (has2 ? expf(pb - mx) : 0.0f);
                #pragma unroll
                for (int s = 32; s > 0; s >>= 1) smv += __shfl_xor(smv, s, 64);
                float lse = logf(smv) + mx;
                pa -= lse;
                if (has2) pb -= lse;
            };
            norm();
            for (int t = 0; t < TT; ++t) {
                float eta = 0.001f / (float)(t + 1);
                float wma = (float)cntg[t * OO + l] * (1.0f / 256.0f);
                pa += eta * ((-5.0f * pa - 1.0f) * wma - (1.0f - wma));
                if (has2) {
                    float wmb = (float)cntg[t * OO + l + 64] * (1.0f / 256.0f);
                    pb += eta * ((-5.0f * pb - 1.0f) * wmb - (1.0f - wmb));
                }
                norm();
            }
            outp[l] = pa;
            if (has2) outp[l + 64] = pb;
            return;
        }

        const int pg = u % 98, og = u / 98;         // og 0..6
        const int p0 = pg * 8, o0 = og * 16;
        const int pl = lane & 7, ol = lane >> 3;    // 8 pl x 8 ol
        const int oA = o0 + ol, oB = oA + 8;
        const int i0 = p0 + pl, i1 = i0 + PAIRS;
        const bool actA = (oA < OO), actB = (oB < OO);

        // rows GLD: lane -> u64 pair (e0, e0+1), e = k*8+pl, 2 slots/GLD
        const int e0 = (lane & 31) * 2;
        const int wk0 = e0 >> 3, wpl0 = e0 & 7;
        const u64* rowg = bitB + (size_t)((wk0 & 3) * INN + (wk0 >> 2) * PAIRS
                                          + p0 + wpl0);
        // wp GLD: lanes<32 win, >=32 post; 1 slot (1KB) per GLD
        const int lw = lane & 31;
        const u64* wpg = (lane < 32) ? winbits : postbits;
        const bool wpact = (o0 + (lw >> 1)) < OO;
        const bool cntact = (lane < 8) && ((o0 + (lane & 3) * 4) < OO);

        auto issueG = [&](int G) {
            int r0 = 2 * G;
            {   // rows: slots r0&15, r0&15+1 (1 GLD, 64 lanes)
                int rr = r0 + (lane >> 5); if (rr > TT - 1) rr = TT - 1;
                GLD16(rowg + (size_t)rr * ROWSTRIDE,
                      (las_p)&sm.f.rows[wv][r0 & 15][0]);
            }
            {   // wp slot r0
                int rr = r0; if (rr > TT - 1) rr = TT - 1;
                if (wpact)
                    GLD16(wpg + ((size_t)rr * OO + o0) * 4 + 2 * lw,
                          (las_p)&sm.f.wp[wv][r0 & 7][0]);
            }
            {   // wp slot r0+1
                int rr = r0 + 1; if (rr > TT - 1) rr = TT - 1;
                if (wpact)
                    GLD16(wpg + ((size_t)rr * OO + o0) * 4 + 2 * lw,
                          (las_p)&sm.f.wp[wv][(r0 + 1) & 7][0]);
            }
            {   // cnt: 2 slots, 8 lanes
                if (cntact) {
                    int rr = r0 + (lane >> 2); if (rr > TT - 1) rr = TT - 1;
                    GLD16(cntg + (size_t)rr * OO + o0 + (lane & 3) * 4,
                          (las_p)&sm.f.cntR[wv][r0 & 7][0]);
                }
            }
        };

        // chain init (clamp + pairwise lse), proven first=1 path
        float aA = actA ? L0[(size_t)i0 * OO + oA] : -1.0f;
        float bA = actA ? L0[(size_t)i1 * OO + oA] : -1.0f;
        float aB = actB ? L0[(size_t)i0 * OO + oB] : -1.0f;
        float bB = actB ? L0[(size_t)i1 * OO + oB] : -1.0f;
        {
            aA = fminf(fmaxf(aA, -5.0f), 0.0f);
            bA = fminf(fmaxf(bA, -5.0f), 0.0f);
            float m = fmaxf(aA, bA), mn = fminf(aA, bA);
            float lse = __logf(1.0f + __expf(mn - m)) + m;
            aA -= lse; bA -= lse;
            aB = fminf(fmaxf(aB, -5.0f), 0.0f);
            bB = fminf(fmaxf(bB, -5.0f), 0.0f);
            float m2 = fmaxf(aB, bB), mn2 = fminf(aB, bB);
            float lse2 = __logf(1.0f + __expf(mn2 - m2)) + m2;
            aB -= lse2; bB -= lse2;
        }

        auto chainstep = [&](int t, int sp) {
            int s = t & 7;
            const u64* wpS = &sm.f.wp[wv][s][0];
            const u64* P = sm.f.potC[wv][sp][pl];
            const u64* Lt = sm.f.ltpC[wv][sp][pl];
            u64 P0 = P[0], P1 = P[1], P2 = P[2], P3 = P[3];
            u64 P4 = P[4], P5 = P[5], P6 = P[6], P7 = P[7];
            u64 Q0 = Lt[0], Q1 = Lt[1], Q2 = Lt[2], Q3 = Lt[3];
            u64 Q4 = Lt[4], Q5 = Lt[5], Q6 = Lt[6], Q7 = Lt[7];
            float eta = 0.001f / (float)(t + 1);
            // ---- chain A ----
            {
                u64 W0 = wpS[ol*4+0], W1 = wpS[ol*4+1], W2 = wpS[ol*4+2], W3 = wpS[ol*4+3];
                u64 S0 = wpS[64+ol*4+0], S1 = wpS[64+ol*4+1], S2 = wpS[64+ol*4+2], S3 = wpS[64+ol*4+3];
                float cw = (float)sm.f.cntR[wv][s][ol];
                float lt0 = (float)(__popcll(Q0&W0)+__popcll(Q1&W1)+__popcll(Q2&W2)+__popcll(Q3&W3));
                float lt1 = (float)(__popcll(Q4&W0)+__popcll(Q5&W1)+__popcll(Q6&W2)+__popcll(Q7&W3));
                float pp0 = (float)(__popcll(P0&S0)+__popcll(P1&S1)+__popcll(P2&S2)+__popcll(P3&S3));
                float pp1 = (float)(__popcll(P4&S0)+__popcll(P5&S1)+__popcll(P6&S2)+__popcll(P7&S3));
                float dw0 = (5.0f*__expf(-aA) - 1.0f)*(lt0*(1.0f/256.0f))
                          + (cw - lt0 - pp0)*(1.0f/256.0f);
                float dw1 = (5.0f*__expf(-bA) - 1.0f)*(lt1*(1.0f/256.0f))
                          + (cw - lt1 - pp1)*(1.0f/256.0f);
                aA += eta*dw0; bA += eta*dw1;
                aA = fminf(fmaxf(aA,-5.0f),0.0f);
                bA = fminf(fmaxf(bA,-5.0f),0.0f);
                float m = fmaxf(aA,bA), mn = fminf(aA,bA);
                float lse = __logf(1.0f + __expf(mn-m)) + m;
                aA -= lse; bA -= lse;
            }
            // ---- chain B ----
            {
                u64 W0 = wpS[(ol+8)*4+0], W1 = wpS[(ol+8)*4+1], W2 = wpS[(ol+8)*4+2], W3 = wpS[(ol+8)*4+3];
                u64 S0 = wpS[64+(ol+8)*4+0], S1 = wpS[64+(ol+8)*4+1], S2 = wpS[64+(ol+8)*4+2], S3 = wpS[64+(ol+8)*4+3];
                float cw = (float)sm.f.cntR[wv][s][ol+8];
                float lt0 = (float)(__popcll(Q0&W0)+__popcll(Q1&W1)+__popcll(Q2&W2)+__popcll(Q3&W3));
                float lt1 = (float)(__popcll(Q4&W0)+__popcll(Q5&W1)+__popcll(Q6&W2)+__popcll(Q7&W3));
                float pp0 = (float)(__popcll(P0&S0)+__popcll(P1&S1)+__popcll(P2&S2)+__popcll(P3&S3));
                float pp1 = (float)(__popcll(P4&S0)+__popcll(P5&S1)+__popcll(P6&S2)+__popcll(P7&S3));
                float dw0 = (5.0f*__expf(-aB) - 1.0f)*(lt0*(1.0f/256.0f))
                          + (cw - lt0 - pp0)*(1.0f/256.0f);
                float dw1 = (5.0f*__expf(-bB) - 1.0f)*(lt1*(1.0f/256.0f))
                          + (cw - lt1 - pp1)*(1.0f/256.0f);
                aB += eta*dw0; bB += eta*dw1;
                aB = fminf(fmaxf(aB,-5.0f),0.0f);
                bB = fminf(fmaxf(bB,-5.0f),0.0f);
                float m = fmaxf(aB,bB), mn = fminf(aB,bB);
                float lse = __logf(1.0f + __expf(mn-m)) + m;
                aB -= lse; bB -= lse;
            }
        };

        issueG(0);
        issueG(1);
        for (int I = 0; I < 100; ++I) {
            issueG(I + 2);
            asm volatile("s_waitcnt vmcnt(8)" ::: "memory");  // group I resident
            // window for steps 2I, 2I+1 (12 ring reads, OR-idempotent clamp)
            int b0 = 2 * I;
            u64 com = 0;
            #pragma unroll
            for (int j = 8; j >= 0; --j) {
                int r = b0 - j; r = (r < 0) ? 0 : r;
                com |= sm.f.rows[wv][r & 15][lane];
            }
            int r9 = b0 - 9;   r9 = (r9 < 0) ? 0 : r9;
            int r10 = b0 - 10; r10 = (r10 < 0) ? 0 : r10;
            u64 v9  = sm.f.rows[wv][r9 & 15][lane];
            u64 v10 = sm.f.rows[wv][r10 & 15][lane];
            u64 vt2 = sm.f.rows[wv][(b0 + 1) & 15][lane];
            u64 pot1 = com | v9;
            u64 pot2 = com | vt2;
            sm.f.potC[wv][0][lane & 7][lane >> 3] = pot1;
            sm.f.potC[wv][1][lane & 7][lane >> 3] = pot2;
            sm.f.ltpC[wv][0][lane & 7][lane >> 3] = pot1 | v10;
            sm.f.ltpC[wv][1][lane & 7][lane >> 3] = pot2 | v9;
            asm volatile("s_waitcnt lgkmcnt(0)" ::: "memory");  // cross-lane publish
            chainstep(b0, 0);
            chainstep(b0 + 1, 1);
        }
        if (actA) {
            outL[(size_t)i0 * OO + oA] = aA;
            outL[(size_t)i1 * OO + oA] = bA;
        }
        if (actB) {
            outL[(size_t)i0 * OO + oB] = aB;
            outL[(size_t)i1 * OO + oB] = bB;
        }
    }
}

extern "C" void kernel_launch(void* const* d_in, const int* in_sizes, int n_in,
                              void* d_out, int out_size, void* d_ws, size_t ws_size,
                              hipStream_t stream) {
    const int*   x  = (const int*)d_in[0];
    const float* L0 = (const float*)d_in[1];
    const float* p0 = (const float*)d_in[2];
    float* out = (float*)d_out;

    char* ws = (char*)d_ws;
    size_t off = 0;
    auto alloc = [&](size_t bytes) -> void* {
        off = (off + 255) & ~(size_t)255;
        void* p = ws + off;
        off += bytes;
        return p;
    };
    uint32_t* syncc    = (uint32_t*)alloc(256);      // [0],[1] sync; [2] C-queue
    uint8_t*  widx     = (uint8_t*) alloc((size_t)TT * BB);
    uint32_t* cntg     = (uint32_t*)alloc((size_t)TT * OO * 4);
    u64*      winbits  = (u64*)     alloc((size_t)TT * OO * 4 * 8);
    u64*      postbits = (u64*)     alloc((size_t)TT * OO * 4 * 8);
    u64*      bitB     = (u64*)     alloc((size_t)TT * 4 * INN * 8);
    (void)ws_size;

    hipMemsetAsync(syncc, 0, 256, stream);   // zero sync/queue counters
    hipLaunchKernelGGL(k_mono, dim3(NBLK), dim3(512), 0, stream,
                       x, L0, p0, syncc, widx, cntg, winbits, postbits, bitB,
                       out, out + (size_t)INN * OO);
}